// Round 9
// baseline (687.797 us; speedup 1.0000x reference)
//
#include <hip/hip_runtime.h>
#include <math.h>

#define Nn 98304
#define Ee 1572864
#define Cc 64
#define Hh 32
#define TT 128              // nodes per dst-tile
#define NT (Nn / TT)        // 768 tiles
#define HB 256              // bucket blocks (one per CU)
#define EPB (Ee / HB)       // 6144 edges per bucket block

// ws layout (4B units):
//   dinv[Nn] | gb[Nn*32] (bf16 x64/row) | aux[HB*NT] | ebuf[Ee] | agg[Nn*64]

// int64 little-endian indices (< 2^31) -> odd 32-bit words are 0. All threads
// check the SAME 16 words -> deterministic agreement.
__device__ __forceinline__ int detect64(const void* ei) {
    const unsigned int* u = (const unsigned int*)ei;
    int is64 = 1;
    #pragma unroll
    for (int i = 0; i < 16; ++i) is64 &= (u[2 * i + 1] == 0u);
    return is64;
}

__device__ __forceinline__ int load_idx(const void* ei, long e, int is64) {
    if (is64) return (int)((const long long*)ei)[e];
    return ((const int*)ei)[e];
}

__device__ __forceinline__ unsigned short f2bf(float x) {
    union { float f; unsigned int u; } v; v.f = x;
    unsigned int r = v.u + 0x7FFFu + ((v.u >> 16) & 1u);   // RNE
    return (unsigned short)(r >> 16);
}
__device__ __forceinline__ float bf2f(unsigned short h) {
    union { unsigned int u; float f; } v; v.u = ((unsigned int)h) << 16;
    return v.f;
}

// Block-local counting sort of this block's EPB edges by dst-tile.
// No global atomics. ebuf region [b*EPB, (b+1)*EPB) fully packed, tile-ordered.
// aux[b*NT + t] = localOff(16b) | cnt<<16 for tile t within block b's region.
__global__ __launch_bounds__(1024) void k_bucket(const void* __restrict__ ei,
                                                 unsigned int* __restrict__ aux,
                                                 unsigned int* __restrict__ ebuf) {
    __shared__ unsigned int hl[NT];
    __shared__ unsigned int off[NT];
    int t = threadIdx.x, b = blockIdx.x;
    if (t < NT) hl[t] = 0;
    __syncthreads();
    int is64 = detect64(ei);
    long e0 = (long)b * EPB;
    #pragma unroll
    for (int i = 0; i < EPB / 1024; ++i) {     // 6 iters
        int d = load_idx(ei, (long)Ee + e0 + i * 1024 + t, is64);
        atomicAdd(&hl[d >> 7], 1u);            // d / TT   (LDS int atomic: native)
    }
    __syncthreads();
    if (t < NT) off[t] = hl[t];
    __syncthreads();
    // inclusive Hillis-Steele scan over 768
    for (int s = 1; s < NT; s <<= 1) {
        unsigned int v = (t < NT && t >= s) ? off[t - s] : 0u;
        __syncthreads();
        if (t < NT) off[t] += v;
        __syncthreads();
    }
    if (t < NT) {
        unsigned int ex = off[t] - hl[t];      // exclusive
        aux[(long)b * NT + t] = ex | (hl[t] << 16);
        off[t] = ex;                           // reuse as cursor
    }
    __syncthreads();
    #pragma unroll
    for (int i = 0; i < EPB / 1024; ++i) {
        long e = e0 + i * 1024 + t;
        int s = load_idx(ei, e, is64);
        int d = load_idx(ei, (long)Ee + e, is64);
        unsigned int pos = atomicAdd(&off[d >> 7], 1u);   // LDS atomic
        ebuf[(long)b * EPB + pos] = (unsigned int)s | ((unsigned int)(d & (TT - 1)) << 17);
    }
}

// per tile: flat-iterate this tile's HB runs (binary search over scanned run
// lengths -> coalesced run-contiguous ebuf reads), LDS int histogram of local
// dst -> dinv. No staging, no scatter.
__global__ __launch_bounds__(256) void k_deg(const unsigned int* __restrict__ aux,
                                             const unsigned int* __restrict__ ebuf,
                                             float* __restrict__ dinv) {
    __shared__ unsigned int rbI[HB];       // inclusive scan of run counts
    __shared__ unsigned int ro[HB];        // run offsets within source block region
    __shared__ unsigned int cnt[TT];
    int t = threadIdx.x, tile = blockIdx.x;
    if (t < HB) {
        unsigned int av = aux[(long)t * NT + tile];
        ro[t] = av & 0xFFFFu;
        rbI[t] = av >> 16;
    }
    if (t < TT) cnt[t] = 0;
    __syncthreads();
    for (int s = 1; s < HB; s <<= 1) {     // inclusive scan over 256
        unsigned int v = (t < HB && t >= s) ? rbI[t - s] : 0u;
        __syncthreads();
        if (t < HB) rbI[t] += v;
        __syncthreads();
    }
    int total = (int)rbI[HB - 1];
    for (int i = t; i < total; i += 256) {
        int pos = 0;
        #pragma unroll
        for (int s = HB / 2; s > 0; s >>= 1)
            if ((int)rbI[pos + s - 1] <= i) pos += s;
        unsigned int prev = pos ? rbI[pos - 1] : 0u;
        unsigned int u = ebuf[(long)pos * EPB + ro[pos] + (unsigned int)i - prev];
        atomicAdd(&cnt[u >> 17], 1u);
    }
    __syncthreads();
    if (t < TT)
        dinv[(long)tile * TT + t] = rsqrtf((float)(cnt[t] + 1));   // +1 self-loop
}

// gb = bf16( (state @ conv_W) * dinv[row] )
__global__ __launch_bounds__(256) void k_gemm(const float* __restrict__ state,
                                              const float* __restrict__ W,
                                              const float* __restrict__ dinv,
                                              unsigned short* __restrict__ gb) {
    __shared__ float Wl[64 * 64];       // [k][c]
    __shared__ float Al[64 * 68];       // [r][k], stride 68
    int t = threadIdx.x;
    long n0 = (long)blockIdx.x * 64;

    const float4* W4 = (const float4*)W;
    float4* Wl4 = (float4*)Wl;
    #pragma unroll
    for (int i = 0; i < 4; ++i) Wl4[i * 256 + t] = W4[i * 256 + t];

    const float4* S4 = (const float4*)(state) + n0 * 16;
    #pragma unroll
    for (int i = 0; i < 4; ++i) {
        int f4 = t + i * 256;
        int r = f4 >> 4, k0 = (f4 & 15) * 4;
        *(float4*)(Al + r * 68 + k0) = S4[f4];
    }
    __syncthreads();

    int r0 = (t >> 4) * 4;
    int c0 = (t & 15) * 4;
    float acc[4][4] = {{0.f}};
    #pragma unroll
    for (int kk = 0; kk < 64; kk += 4) {
        float4 a4[4], w4[4];
        #pragma unroll
        for (int i = 0; i < 4; ++i) a4[i] = *(const float4*)(Al + (r0 + i) * 68 + kk);
        #pragma unroll
        for (int j = 0; j < 4; ++j) w4[j] = *(const float4*)(Wl + (kk + j) * 64 + c0);
        const float* aa = (const float*)a4;
        const float* ww = (const float*)w4;
        #pragma unroll
        for (int i = 0; i < 4; ++i)
            #pragma unroll
            for (int j = 0; j < 4; ++j) {
                float av = aa[i * 4 + j];
                #pragma unroll
                for (int c = 0; c < 4; ++c)
                    acc[i][c] = fmaf(av, ww[j * 4 + c], acc[i][c]);
            }
    }
    #pragma unroll
    for (int i = 0; i < 4; ++i) {
        long n = n0 + r0 + i;
        float dv = dinv[n];
        ushort4 o;
        o.x = f2bf(acc[i][0] * dv); o.y = f2bf(acc[i][1] * dv);
        o.z = f2bf(acc[i][2] * dv); o.w = f2bf(acc[i][3] * dv);
        *(ushort4*)(gb + n * 64 + c0) = o;
    }
}

// per tile: acc[128][64] fp32 in LDS, init with self-loop term, stream this
// tile's edges straight from ebuf runs (binsearch flat iteration), accumulate
// messages via native ds_add_f32 (unsafeAtomicAdd), write agg = acc * dinv.
__global__ __launch_bounds__(1024) void k_tile(const unsigned int* __restrict__ aux,
                                               const unsigned int* __restrict__ ebuf,
                                               const unsigned short* __restrict__ gb,
                                               const float* __restrict__ dinv,
                                               float* __restrict__ agg) {
    __shared__ float acc[TT * 64];         // 32 KB
    __shared__ unsigned int rbI[HB];
    __shared__ unsigned int ro[HB];
    int t = threadIdx.x, tile = blockIdx.x;
    int wave = t >> 6, lane = t & 63;
    long nbase = (long)tile * TT;
    if (t < HB) {
        unsigned int av = aux[(long)t * NT + tile];
        ro[t] = av & 0xFFFFu;
        rbI[t] = av >> 16;
    }
    // init acc with self-loop term (gb pre-scaled by dinv[src])
    #pragma unroll
    for (int i = 0; i < TT * 64 / 1024; ++i)
        acc[i * 1024 + t] = bf2f(gb[nbase * 64 + i * 1024 + t]);
    __syncthreads();
    for (int s = 1; s < HB; s <<= 1) {     // inclusive scan over 256
        unsigned int v = (t < HB && t >= s) ? rbI[t - s] : 0u;
        __syncthreads();
        if (t < HB) rbI[t] += v;
        __syncthreads();
    }
    int total = (int)rbI[HB - 1];
    for (int base = wave * 64; base < total; base += 1024) {
        int m = min(64, total - base);
        int i = min(base + lane, total - 1);
        int pos = 0;
        #pragma unroll
        for (int s = HB / 2; s > 0; s >>= 1)
            if ((int)rbI[pos + s - 1] <= i) pos += s;
        unsigned int prev = pos ? rbI[pos - 1] : 0u;
        unsigned int ev = ebuf[(long)pos * EPB + ro[pos] + (unsigned int)i - prev];
        int j = 0;
        for (; j + 8 <= m; j += 8) {
            unsigned int u0 = __shfl(ev, j,     64);
            unsigned int u1 = __shfl(ev, j + 1, 64);
            unsigned int u2 = __shfl(ev, j + 2, 64);
            unsigned int u3 = __shfl(ev, j + 3, 64);
            unsigned int u4 = __shfl(ev, j + 4, 64);
            unsigned int u5 = __shfl(ev, j + 5, 64);
            unsigned int u6 = __shfl(ev, j + 6, 64);
            unsigned int u7 = __shfl(ev, j + 7, 64);
            float v0 = bf2f(gb[(long)(u0 & 0x1FFFF) * 64 + lane]);
            float v1 = bf2f(gb[(long)(u1 & 0x1FFFF) * 64 + lane]);
            float v2 = bf2f(gb[(long)(u2 & 0x1FFFF) * 64 + lane]);
            float v3 = bf2f(gb[(long)(u3 & 0x1FFFF) * 64 + lane]);
            float v4 = bf2f(gb[(long)(u4 & 0x1FFFF) * 64 + lane]);
            float v5 = bf2f(gb[(long)(u5 & 0x1FFFF) * 64 + lane]);
            float v6 = bf2f(gb[(long)(u6 & 0x1FFFF) * 64 + lane]);
            float v7 = bf2f(gb[(long)(u7 & 0x1FFFF) * 64 + lane]);
            unsafeAtomicAdd(&acc[(u0 >> 17) * 64 + lane], v0);   // ds_add_f32
            unsafeAtomicAdd(&acc[(u1 >> 17) * 64 + lane], v1);
            unsafeAtomicAdd(&acc[(u2 >> 17) * 64 + lane], v2);
            unsafeAtomicAdd(&acc[(u3 >> 17) * 64 + lane], v3);
            unsafeAtomicAdd(&acc[(u4 >> 17) * 64 + lane], v4);
            unsafeAtomicAdd(&acc[(u5 >> 17) * 64 + lane], v5);
            unsafeAtomicAdd(&acc[(u6 >> 17) * 64 + lane], v6);
            unsafeAtomicAdd(&acc[(u7 >> 17) * 64 + lane], v7);
        }
        for (; j < m; ++j) {
            unsigned int u = __shfl(ev, j, 64);
            float v = bf2f(gb[(long)(u & 0x1FFFF) * 64 + lane]);
            unsafeAtomicAdd(&acc[(u >> 17) * 64 + lane], v);
        }
    }
    __syncthreads();
    #pragma unroll
    for (int i = 0; i < TT * 64 / 1024; ++i) {
        int idx = i * 1024 + t;
        agg[nbase * 64 + idx] = acc[idx] * dinv[nbase + (idx >> 6)];
    }
}

// relu(agg + conv_b) + state -> MLP 64->32->32->1 -> softplus + 1e-20
__global__ __launch_bounds__(128) void k_final(const float* __restrict__ agg,
                                               const float* __restrict__ state,
                                               const float* __restrict__ conv_b,
                                               const float* __restrict__ W1,
                                               const float* __restrict__ b1,
                                               const float* __restrict__ W2,
                                               const float* __restrict__ b2,
                                               const float* __restrict__ W3,
                                               const float* __restrict__ b3,
                                               float* __restrict__ out) {
    __shared__ float sW1[Cc * Hh];
    __shared__ float sW2[Hh * Hh];
    __shared__ float sW3[Hh], sb1[Hh], sb2[Hh], scb[Cc];
    __shared__ float sb3;
    int t = threadIdx.x;
    for (int i = t; i < Cc * Hh; i += 128) sW1[i] = W1[i];
    for (int i = t; i < Hh * Hh; i += 128) sW2[i] = W2[i];
    if (t < Hh) { sW3[t] = W3[t]; sb1[t] = b1[t]; sb2[t] = b2[t]; }
    if (t >= 32 && t < 96) scb[t - 32] = conv_b[t - 32];
    if (t == 127) sb3 = b3[0];
    __syncthreads();

    int n = blockIdx.x * 128 + t;
    const float4* a4p = (const float4*)(agg + (long)n * 64);
    const float4* s4p = (const float4*)(state + (long)n * 64);
    float x[Cc];
    #pragma unroll
    for (int k4 = 0; k4 < 16; ++k4) {
        float4 a = a4p[k4];
        float4 s = s4p[k4];
        x[k4 * 4 + 0] = fmaxf(a.x + scb[k4 * 4 + 0], 0.f) + s.x;
        x[k4 * 4 + 1] = fmaxf(a.y + scb[k4 * 4 + 1], 0.f) + s.y;
        x[k4 * 4 + 2] = fmaxf(a.z + scb[k4 * 4 + 2], 0.f) + s.z;
        x[k4 * 4 + 3] = fmaxf(a.w + scb[k4 * 4 + 3], 0.f) + s.w;
    }
    float h1[Hh];
    #pragma unroll
    for (int j = 0; j < Hh; ++j) h1[j] = sb1[j];
    #pragma unroll
    for (int k = 0; k < Cc; ++k) {
        float xv = x[k];
        #pragma unroll
        for (int j = 0; j < Hh; ++j) h1[j] = fmaf(xv, sW1[k * Hh + j], h1[j]);
    }
    #pragma unroll
    for (int j = 0; j < Hh; ++j) h1[j] = fmaxf(h1[j], 0.f);

    float h2[Hh];
    #pragma unroll
    for (int j = 0; j < Hh; ++j) h2[j] = sb2[j];
    #pragma unroll
    for (int k = 0; k < Hh; ++k) {
        float xv = h1[k];
        #pragma unroll
        for (int j = 0; j < Hh; ++j) h2[j] = fmaf(xv, sW2[k * Hh + j], h2[j]);
    }
    float y = sb3;
    #pragma unroll
    for (int j = 0; j < Hh; ++j) y = fmaf(fmaxf(h2[j], 0.f), sW3[j], y);

    float sp = fmaxf(y, 0.f) + log1pf(expf(-fabsf(y)));
    out[n] = sp + 1e-20f;
}

extern "C" void kernel_launch(void* const* d_in, const int* in_sizes, int n_in,
                              void* d_out, int out_size, void* d_ws, size_t ws_size,
                              hipStream_t stream) {
    const float* state  = (const float*)d_in[0];
    const void*  ei     = d_in[1];
    const float* conv_W = (const float*)d_in[2];
    const float* conv_b = (const float*)d_in[3];
    const float* W1 = (const float*)d_in[4];
    const float* b1 = (const float*)d_in[5];
    const float* W2 = (const float*)d_in[6];
    const float* b2 = (const float*)d_in[7];
    const float* W3 = (const float*)d_in[8];
    const float* b3 = (const float*)d_in[9];
    float* out = (float*)d_out;

    float*          dinv = (float*)d_ws;
    unsigned short* gb   = (unsigned short*)(dinv + Nn);
    unsigned int*   aux  = (unsigned int*)(gb + (size_t)Nn * 64);
    unsigned int*   ebuf = aux + (size_t)HB * NT;
    float*          agg  = (float*)(ebuf + Ee);

    k_bucket<<<HB, 1024, 0, stream>>>(ei, aux, ebuf);
    k_deg<<<NT, 256, 0, stream>>>(aux, ebuf, dinv);
    k_gemm<<<Nn / 64, 256, 0, stream>>>(state, conv_W, dinv, gb);
    k_tile<<<NT, 1024, 0, stream>>>(aux, ebuf, gb, dinv, agg);
    k_final<<<Nn / 128, 128, 0, stream>>>(agg, state, conv_b,
                                          W1, b1, W2, b2, W3, b3, out);
}

// Round 11
// 201.715 us; speedup vs baseline: 3.4098x; 3.4098x over previous
//
#include <hip/hip_runtime.h>
#include <math.h>

#define Nn 98304
#define Ee 1572864
#define Cc 64
#define Hh 32
#define TT 128              // nodes per dst-tile
#define NT (Nn / TT)        // 768 tiles
#define HB 256              // bucket blocks (one per CU)
#define EPB (Ee / HB)       // 6144 edges per bucket block
#define CAPT 2560           // staged edges per tile (mean 2048, sigma~45 -> +11 sigma)

// ws layout (4B units):
//   dinv[Nn] | gb[Nn*32] (bf16 x64/row) | rowOff[Nn] | rowEnd[Nn]
//   | aux[HB*NT] | ebuf[Ee] | srcs[NT*CAPT] | agg[Nn*64]

// int64 little-endian indices (< 2^31) -> odd 32-bit words are 0. All threads
// check the SAME 16 words -> deterministic agreement.
__device__ __forceinline__ int detect64(const void* ei) {
    const unsigned int* u = (const unsigned int*)ei;
    int is64 = 1;
    #pragma unroll
    for (int i = 0; i < 16; ++i) is64 &= (u[2 * i + 1] == 0u);
    return is64;
}

__device__ __forceinline__ int load_idx(const void* ei, long e, int is64) {
    if (is64) return (int)((const long long*)ei)[e];
    return ((const int*)ei)[e];
}

__device__ __forceinline__ unsigned short f2bf(float x) {
    union { float f; unsigned int u; } v; v.f = x;
    unsigned int r = v.u + 0x7FFFu + ((v.u >> 16) & 1u);   // RNE
    return (unsigned short)(r >> 16);
}
__device__ __forceinline__ float bf2f(unsigned short h) {
    union { unsigned int u; float f; } v; v.u = ((unsigned int)h) << 16;
    return v.f;
}

// Two-pass block-local counting sort of this block's EPB edges by dst-tile
// (exact structure that passed in round 9). No global atomics. ebuf region
// [b*EPB,(b+1)*EPB) fully packed; aux[b*NT+t] = localOff(16b) | cnt<<16.
__global__ __launch_bounds__(1024) void k_bucket(const void* __restrict__ ei,
                                                 unsigned int* __restrict__ aux,
                                                 unsigned int* __restrict__ ebuf) {
    __shared__ unsigned int hl[NT];
    __shared__ unsigned int off[NT];
    int t = threadIdx.x, b = blockIdx.x;
    if (t < NT) hl[t] = 0;
    __syncthreads();
    int is64 = detect64(ei);
    long e0 = (long)b * EPB;
    #pragma unroll
    for (int i = 0; i < EPB / 1024; ++i) {     // 6 iters
        int d = load_idx(ei, (long)Ee + e0 + i * 1024 + t, is64);
        atomicAdd(&hl[d >> 7], 1u);            // d / TT   (LDS int atomic: native)
    }
    __syncthreads();
    if (t < NT) off[t] = hl[t];
    __syncthreads();
    // inclusive Hillis-Steele scan over 768
    for (int s = 1; s < NT; s <<= 1) {
        unsigned int v = (t < NT && t >= s) ? off[t - s] : 0u;
        __syncthreads();
        if (t < NT) off[t] += v;
        __syncthreads();
    }
    if (t < NT) {
        unsigned int ex = off[t] - hl[t];      // exclusive
        aux[(long)b * NT + t] = ex | (hl[t] << 16);
        off[t] = ex;                           // reuse as cursor
    }
    __syncthreads();
    #pragma unroll
    for (int i = 0; i < EPB / 1024; ++i) {
        long e = e0 + i * 1024 + t;
        int s = load_idx(ei, e, is64);
        int d = load_idx(ei, (long)Ee + e, is64);
        unsigned int pos = atomicAdd(&off[d >> 7], 1u);   // LDS atomic
        ebuf[(long)b * EPB + pos] = (unsigned int)s | ((unsigned int)(d & (TT - 1)) << 17);
    }
}

// per tile: stage this tile's HB runs into LDS via binary-search flat copy
// (run-contiguous ebuf reads), count local dsts (-> dinv, rowOff, rowEnd),
// scatter src into tile-private srcs region.
__global__ __launch_bounds__(256) void k_nodecnt(const unsigned int* __restrict__ aux,
                                                 const unsigned int* __restrict__ ebuf,
                                                 unsigned int* __restrict__ rowOff,
                                                 unsigned int* __restrict__ rowEnd,
                                                 float* __restrict__ dinv,
                                                 unsigned int* __restrict__ srcs) {
    __shared__ unsigned int stage[CAPT];   // 10 KB
    __shared__ unsigned int rbI[HB];       // inclusive scan of run counts
    __shared__ unsigned int ro[HB];        // run offsets within source block region
    __shared__ unsigned int cnt[TT];
    __shared__ unsigned int sc[TT];
    __shared__ unsigned int cur[TT];
    int t = threadIdx.x, tile = blockIdx.x;
    if (t < HB) {
        unsigned int av = aux[(long)t * NT + tile];
        ro[t] = av & 0xFFFFu;
        rbI[t] = av >> 16;
    }
    __syncthreads();
    for (int s = 1; s < HB; s <<= 1) {     // inclusive scan over 256
        unsigned int v = (t < HB && t >= s) ? rbI[t - s] : 0u;
        __syncthreads();
        if (t < HB) rbI[t] += v;
        __syncthreads();
    }
    int total = (int)rbI[HB - 1];
    // flat copy: element i -> run (8-step binary search), run-contiguous reads
    for (int i = t; i < total; i += 256) {
        int pos = 0;
        #pragma unroll
        for (int s = HB / 2; s > 0; s >>= 1)
            if ((int)rbI[pos + s - 1] <= i) pos += s;
        unsigned int prev = pos ? rbI[pos - 1] : 0u;
        stage[i] = ebuf[(long)pos * EPB + ro[pos] + (unsigned int)i - prev];
    }
    if (t < TT) cnt[t] = 0;
    __syncthreads();
    for (int i = t; i < total; i += 256)
        atomicAdd(&cnt[stage[i] >> 17], 1u);
    __syncthreads();
    if (t < TT) sc[t] = cnt[t];
    __syncthreads();
    #pragma unroll
    for (int off = 1; off < TT; off <<= 1) {
        unsigned int v = (t >= off && t < TT) ? sc[t - off] : 0u;
        __syncthreads();
        if (t < TT) sc[t] += v;
        __syncthreads();
    }
    if (t < TT) {
        unsigned int start = (unsigned int)(tile * CAPT) + sc[t] - cnt[t];
        rowOff[(long)tile * TT + t] = start;
        rowEnd[(long)tile * TT + t] = start + cnt[t];
        cur[t] = start;
        dinv[(long)tile * TT + t] = rsqrtf((float)(cnt[t] + 1));   // +1 self-loop
    }
    __syncthreads();
    for (int i = t; i < total; i += 256) {
        unsigned int u = stage[i];
        unsigned int pos = atomicAdd(&cur[u >> 17], 1u);
        srcs[pos] = u & 0x1FFFFu;
    }
}

// gb = bf16( (state @ conv_W) * dinv[row] )
__global__ __launch_bounds__(256) void k_gemm(const float* __restrict__ state,
                                              const float* __restrict__ W,
                                              const float* __restrict__ dinv,
                                              unsigned short* __restrict__ gb) {
    __shared__ float Wl[64 * 64];       // [k][c]
    __shared__ float Al[64 * 68];       // [r][k], stride 68
    int t = threadIdx.x;
    long n0 = (long)blockIdx.x * 64;

    const float4* W4 = (const float4*)W;
    float4* Wl4 = (float4*)Wl;
    #pragma unroll
    for (int i = 0; i < 4; ++i) Wl4[i * 256 + t] = W4[i * 256 + t];

    const float4* S4 = (const float4*)(state) + n0 * 16;
    #pragma unroll
    for (int i = 0; i < 4; ++i) {
        int f4 = t + i * 256;
        int r = f4 >> 4, k0 = (f4 & 15) * 4;
        *(float4*)(Al + r * 68 + k0) = S4[f4];
    }
    __syncthreads();

    int r0 = (t >> 4) * 4;
    int c0 = (t & 15) * 4;
    float acc[4][4] = {{0.f}};
    #pragma unroll
    for (int kk = 0; kk < 64; kk += 4) {
        float4 a4[4], w4[4];
        #pragma unroll
        for (int i = 0; i < 4; ++i) a4[i] = *(const float4*)(Al + (r0 + i) * 68 + kk);
        #pragma unroll
        for (int j = 0; j < 4; ++j) w4[j] = *(const float4*)(Wl + (kk + j) * 64 + c0);
        const float* aa = (const float*)a4;
        const float* ww = (const float*)w4;
        #pragma unroll
        for (int i = 0; i < 4; ++i)
            #pragma unroll
            for (int j = 0; j < 4; ++j) {
                float av = aa[i * 4 + j];
                #pragma unroll
                for (int c = 0; c < 4; ++c)
                    acc[i][c] = fmaf(av, ww[j * 4 + c], acc[i][c]);
            }
    }
    #pragma unroll
    for (int i = 0; i < 4; ++i) {
        long n = n0 + r0 + i;
        float dv = dinv[n];
        ushort4 o;
        o.x = f2bf(acc[i][0] * dv); o.y = f2bf(acc[i][1] * dv);
        o.z = f2bf(acc[i][2] * dv); o.w = f2bf(acc[i][3] * dv);
        *(ushort4*)(gb + n * 64 + c0) = o;
    }
}

// agg[n] = dinv[n] * (g[n] + sum_{src in row(n)} g[src])   (one wave per node)
__global__ __launch_bounds__(256) void k_gather(const unsigned int* __restrict__ rowOff,
                                                const unsigned int* __restrict__ rowEnd,
                                                const unsigned int* __restrict__ srcs,
                                                const unsigned short* __restrict__ gb,
                                                const float* __restrict__ dinv,
                                                float* __restrict__ agg) {
    int wave = threadIdx.x >> 6, lane = threadIdx.x & 63;
    int n = blockIdx.x * 4 + wave;
    int start = (int)rowOff[n];
    int end = (int)rowEnd[n];
    float acc = bf2f(gb[(long)n * 64 + lane]);   // self-loop term
    for (int base = start; base < end; base += 64) {
        int m = min(64, end - base);
        int sv = (lane < m) ? (int)srcs[base + lane] : 0;
        int j = 0;
        for (; j + 8 <= m; j += 8) {
            int s0 = __shfl(sv, j,     64);
            int s1 = __shfl(sv, j + 1, 64);
            int s2 = __shfl(sv, j + 2, 64);
            int s3 = __shfl(sv, j + 3, 64);
            int s4 = __shfl(sv, j + 4, 64);
            int s5 = __shfl(sv, j + 5, 64);
            int s6 = __shfl(sv, j + 6, 64);
            int s7 = __shfl(sv, j + 7, 64);
            float v0 = bf2f(gb[(long)s0 * 64 + lane]);
            float v1 = bf2f(gb[(long)s1 * 64 + lane]);
            float v2 = bf2f(gb[(long)s2 * 64 + lane]);
            float v3 = bf2f(gb[(long)s3 * 64 + lane]);
            float v4 = bf2f(gb[(long)s4 * 64 + lane]);
            float v5 = bf2f(gb[(long)s5 * 64 + lane]);
            float v6 = bf2f(gb[(long)s6 * 64 + lane]);
            float v7 = bf2f(gb[(long)s7 * 64 + lane]);
            acc += ((v0 + v1) + (v2 + v3)) + ((v4 + v5) + (v6 + v7));
        }
        for (; j + 4 <= m; j += 4) {
            int s0 = __shfl(sv, j,     64);
            int s1 = __shfl(sv, j + 1, 64);
            int s2 = __shfl(sv, j + 2, 64);
            int s3 = __shfl(sv, j + 3, 64);
            float v0 = bf2f(gb[(long)s0 * 64 + lane]);
            float v1 = bf2f(gb[(long)s1 * 64 + lane]);
            float v2 = bf2f(gb[(long)s2 * 64 + lane]);
            float v3 = bf2f(gb[(long)s3 * 64 + lane]);
            acc += (v0 + v1) + (v2 + v3);
        }
        for (; j < m; ++j) {
            int s = __shfl(sv, j, 64);
            acc += bf2f(gb[(long)s * 64 + lane]);
        }
    }
    agg[(long)n * 64 + lane] = acc * dinv[n];
}

// relu(agg + conv_b) + state -> MLP 64->32->32->1 -> softplus + 1e-20
// 128 threads x 768 blocks = exactly 3 blocks/CU (balanced).
__global__ __launch_bounds__(128) void k_final(const float* __restrict__ agg,
                                               const float* __restrict__ state,
                                               const float* __restrict__ conv_b,
                                               const float* __restrict__ W1,
                                               const float* __restrict__ b1,
                                               const float* __restrict__ W2,
                                               const float* __restrict__ b2,
                                               const float* __restrict__ W3,
                                               const float* __restrict__ b3,
                                               float* __restrict__ out) {
    __shared__ float sW1[Cc * Hh];
    __shared__ float sW2[Hh * Hh];
    __shared__ float sW3[Hh], sb1[Hh], sb2[Hh], scb[Cc];
    __shared__ float sb3;
    int t = threadIdx.x;
    for (int i = t; i < Cc * Hh; i += 128) sW1[i] = W1[i];
    for (int i = t; i < Hh * Hh; i += 128) sW2[i] = W2[i];
    if (t < Hh) { sW3[t] = W3[t]; sb1[t] = b1[t]; sb2[t] = b2[t]; }
    if (t >= 32 && t < 96) scb[t - 32] = conv_b[t - 32];
    if (t == 127) sb3 = b3[0];
    __syncthreads();

    int n = blockIdx.x * 128 + t;
    const float4* a4p = (const float4*)(agg + (long)n * 64);
    const float4* s4p = (const float4*)(state + (long)n * 64);
    float x[Cc];
    #pragma unroll
    for (int k4 = 0; k4 < 16; ++k4) {
        float4 a = a4p[k4];
        float4 s = s4p[k4];
        x[k4 * 4 + 0] = fmaxf(a.x + scb[k4 * 4 + 0], 0.f) + s.x;
        x[k4 * 4 + 1] = fmaxf(a.y + scb[k4 * 4 + 1], 0.f) + s.y;
        x[k4 * 4 + 2] = fmaxf(a.z + scb[k4 * 4 + 2], 0.f) + s.z;
        x[k4 * 4 + 3] = fmaxf(a.w + scb[k4 * 4 + 3], 0.f) + s.w;
    }
    float h1[Hh];
    #pragma unroll
    for (int j = 0; j < Hh; ++j) h1[j] = sb1[j];
    #pragma unroll
    for (int k = 0; k < Cc; ++k) {
        float xv = x[k];
        #pragma unroll
        for (int j = 0; j < Hh; ++j) h1[j] = fmaf(xv, sW1[k * Hh + j], h1[j]);
    }
    #pragma unroll
    for (int j = 0; j < Hh; ++j) h1[j] = fmaxf(h1[j], 0.f);

    float h2[Hh];
    #pragma unroll
    for (int j = 0; j < Hh; ++j) h2[j] = sb2[j];
    #pragma unroll
    for (int k = 0; k < Hh; ++k) {
        float xv = h1[k];
        #pragma unroll
        for (int j = 0; j < Hh; ++j) h2[j] = fmaf(xv, sW2[k * Hh + j], h2[j]);
    }
    float y = sb3;
    #pragma unroll
    for (int j = 0; j < Hh; ++j) y = fmaf(fmaxf(h2[j], 0.f), sW3[j], y);

    float sp = fmaxf(y, 0.f) + log1pf(expf(-fabsf(y)));
    out[n] = sp + 1e-20f;
}

extern "C" void kernel_launch(void* const* d_in, const int* in_sizes, int n_in,
                              void* d_out, int out_size, void* d_ws, size_t ws_size,
                              hipStream_t stream) {
    const float* state  = (const float*)d_in[0];
    const void*  ei     = d_in[1];
    const float* conv_W = (const float*)d_in[2];
    const float* conv_b = (const float*)d_in[3];
    const float* W1 = (const float*)d_in[4];
    const float* b1 = (const float*)d_in[5];
    const float* W2 = (const float*)d_in[6];
    const float* b2 = (const float*)d_in[7];
    const float* W3 = (const float*)d_in[8];
    const float* b3 = (const float*)d_in[9];
    float* out = (float*)d_out;

    float*          dinv   = (float*)d_ws;
    unsigned short* gb     = (unsigned short*)(dinv + Nn);
    unsigned int*   rowOff = (unsigned int*)(gb + (size_t)Nn * 64);
    unsigned int*   rowEnd = rowOff + Nn;
    unsigned int*   aux    = rowEnd + Nn;
    unsigned int*   ebuf   = aux + (size_t)HB * NT;
    unsigned int*   srcs   = ebuf + Ee;
    float*          agg    = (float*)(srcs + (size_t)NT * CAPT);

    k_bucket<<<HB, 1024, 0, stream>>>(ei, aux, ebuf);
    k_nodecnt<<<NT, 256, 0, stream>>>(aux, ebuf, rowOff, rowEnd, dinv, srcs);
    k_gemm<<<Nn / 64, 256, 0, stream>>>(state, conv_W, dinv, gb);
    k_gather<<<Nn / 4, 256, 0, stream>>>(rowOff, rowEnd, srcs, gb, dinv, agg);
    k_final<<<Nn / 128, 128, 0, stream>>>(agg, state, conv_b,
                                          W1, b1, W2, b2, W3, b3, out);
}